// Round 2
// baseline (287.140 us; speedup 1.0000x reference)
//
#include <hip/hip_runtime.h>

#define BATCH 512
#define SEQ   512
#define VOCAB 1000
#define EMB   100
#define UNITS 64

typedef float v2f __attribute__((ext_vector_type(2)));
typedef int   v2i __attribute__((ext_vector_type(2)));

// ---------------------------------------------------------------------------
// Kernel 1: P[v][u] = sum_d emb[v][d] * Wxh[d][u] + b[u]   (VOCAB x UNITS)
// ---------------------------------------------------------------------------
__global__ __launch_bounds__(256) void proj_kernel(
    const float* __restrict__ emb, const float* __restrict__ Wxh,
    const float* __restrict__ bias, float* __restrict__ P) {
  const int v = blockIdx.x * 4 + (threadIdx.x >> 6);
  const int u = threadIdx.x & 63;
  const float* e = emb + v * EMB;
  float a0 = 0.f, a1 = 0.f, a2 = 0.f, a3 = 0.f;
#pragma unroll
  for (int d = 0; d < EMB; d += 4) {
    a0 = fmaf(e[d + 0], Wxh[(d + 0) * UNITS + u], a0);
    a1 = fmaf(e[d + 1], Wxh[(d + 1) * UNITS + u], a1);
    a2 = fmaf(e[d + 2], Wxh[(d + 2) * UNITS + u], a2);
    a3 = fmaf(e[d + 3], Wxh[(d + 3) * UNITS + u], a3);
  }
  P[v * UNITS + u] = ((a0 + a1) + (a2 + a3)) + bias[u];
}

// DPP-source add: returns x[lane ^ perm] + x[lane] for full-permutation dpp
// controls (all lanes valid). CTRL must be an ICE -> template parameter.
template <int CTRL>
__device__ __forceinline__ float dpp_add(float x) {
  int t = __builtin_amdgcn_update_dpp(0, __float_as_int(x), CTRL, 0xF, 0xF, true);
  return __int_as_float(t) + x;
}

// ---------------------------------------------------------------------------
// Kernel 2: sequential scan, ONE wave per batch row. ZERO LDS on the chain.
//
// r1 post-mortem: 492 cyc/step, only ~107 of which is VALU issue; the rest is
// the LDS h-publish round trip (ds_write -> in-order DS pipe -> ds_read
// latency) on the serial chain. This version keeps h PER-LANE IN REGISTER and
// does the matvec y = h @ Whh as a 6-stage register butterfly reduce-scatter:
//
//   products: lane l holds row W[l][.] (64 VGPR); p[r] = h_l * W[l][j(r,c)]
//   S1: xor32 via permlane32_swap pair-trick + pk_add   (16 pairs x 3 instr)
//   S2: xor16 via permlane16_swap pair-trick + pk_add   ( 8 pairs x 3)
//   S3: xor8  via DPP row_ror:8  adds + cndmask select  ( 4 pairs x 6)
//   S4: xor7  via DPP row_half_mirror (= l^7 within 8)  ( 2 pairs x 6)
//   S5: xor2  via DPP quad_perm[2,3,0,1]                ( 1 pair  x 6)
//   S6: xor1  via DPP quad_perm[1,0,3,2]                ( 3 )
//
// Stage masks {32,16,8,7,2,1} are linearly independent; keep-side functions
// are the dual basis: s1..s6 = b5, b4, b3, b2, b2^b1, b2^b0. Output j is
// labeled t_i(j) = u_i . j with u = {32,16,8,4,6,5}, which makes the final
// scalar at lane l be exactly y[l] (j5..j0 = b5,b4,b3,b2,b1,b0). Weight
// columns are pre-permuted at load to match: reg r comp c holds column
//   j(r,c) = ((r>>1)<<2) | (((r^(r>>1))&1)<<1) | (((r>>1)&1)^c).
// ---------------------------------------------------------------------------
__global__ __launch_bounds__(64)
__attribute__((amdgpu_waves_per_eu(1, 1)))
void scan_kernel(
    const int* __restrict__ tok, const float* __restrict__ P,
    const float* __restrict__ Whh, const float* __restrict__ Wout,
    const float* __restrict__ bout, float* __restrict__ out) {
  const int row  = blockIdx.x;
  const int lane = threadIdx.x;

  // Keep-side predicates (loop-invariant; compiler hoists v_cmp -> sgpr mask).
  const bool k3 = (lane >> 3) & 1;          // s3 = b3
  const bool k4 = (lane >> 2) & 1;          // s4 = b2
  const bool k5 = ((lane >> 2) ^ (lane >> 1)) & 1;  // s5 = b2^b1
  const bool k6 = ((lane >> 2) ^ lane) & 1;          // s6 = b2^b0

  // Weight row l of Whh, columns permuted to the butterfly labeling.
  v2f wp[UNITS / 2];
  const float* wr = Whh + lane * UNITS;
#pragma unroll
  for (int r = 0; r < UNITS / 2; ++r) {
    const int t = r >> 1;
    const int jb = (t << 2) | (((r ^ t) & 1) << 1);
    float wx = wr[jb | ((t & 1) ^ 0)];
    float wy = wr[jb | ((t & 1) ^ 1)];
    asm volatile("" : "+v"(wx), "+v"(wy));
    wp[r].x = wx;
    wp[r].y = wy;
  }

  // All 512 tokens of this row, pre-scaled by UNITS (coalesced loads).
  int tokv[SEQ / 64];
  const int* trow = tok + (long)row * SEQ;
#pragma unroll
  for (int c = 0; c < SEQ / 64; ++c) {
    int t = trow[c * 64 + lane] * UNITS;
    asm volatile("" : "+v"(t));
    tokv[c] = t;
  }

  float h = 0.f;  // h[lane], lives in a register for the whole scan

  // Prefetch P row for t=0.
  int tk0 = __builtin_amdgcn_readlane(tokv[0], 0);
  float a = P[(long)tk0 + lane];

#pragma unroll
  for (int c = 0; c < SEQ / 64; ++c) {
#pragma unroll 2
    for (int tt = 0; tt < 64; ++tt) {
      float a_cur = a;
      // Prefetch next timestep's P row (consumed one full step later).
      int ntt = (tt + 1) & 63;
      int tkn = __builtin_amdgcn_readlane(tokv[c], ntt);
      a = P[(long)tkn + lane];

      // ---- Products: p[r] = h_l * W[l][j(r,.)]  (32 pk_mul) ----
      v2f hh; hh.x = h; hh.y = h;
      v2f p[UNITS / 2];
#pragma unroll
      for (int r = 0; r < UNITS / 2; ++r) p[r] = hh * wp[r];

      // ---- S1: xor32 (permlane32_swap: dst lanes 32-63 <-> src lanes 0-31)
#pragma unroll
      for (int r = 0; r < 16; ++r) {
        v2i sx = __builtin_amdgcn_permlane32_swap(
            __float_as_int(p[r].x), __float_as_int(p[r + 16].x), false, false);
        v2i sy = __builtin_amdgcn_permlane32_swap(
            __float_as_int(p[r].y), __float_as_int(p[r + 16].y), false, false);
        v2f xn, yn;
        xn.x = __int_as_float(sx[0]); yn.x = __int_as_float(sx[1]);
        xn.y = __int_as_float(sy[0]); yn.y = __int_as_float(sy[1]);
        p[r] = xn + yn;  // lo lanes: t1=0 coset sum; hi lanes: t1=1
      }

      // ---- S2: xor16 (permlane16_swap: dst odd 16-rows <-> src even rows)
#pragma unroll
      for (int r = 0; r < 8; ++r) {
#if __has_builtin(__builtin_amdgcn_permlane16_swap)
        v2i sx = __builtin_amdgcn_permlane16_swap(
            __float_as_int(p[r].x), __float_as_int(p[r + 8].x), false, false);
        v2i sy = __builtin_amdgcn_permlane16_swap(
            __float_as_int(p[r].y), __float_as_int(p[r + 8].y), false, false);
        v2f xn, yn;
        xn.x = __int_as_float(sx[0]); yn.x = __int_as_float(sx[1]);
        xn.y = __int_as_float(sy[0]); yn.y = __int_as_float(sy[1]);
        p[r] = xn + yn;
#else
        // select-style fallback: s2 = b4
        const bool k2 = (lane >> 4) & 1;
        float sXx = p[r].x + __shfl_xor(p[r].x, 16);
        float sXy = p[r].y + __shfl_xor(p[r].y, 16);
        float sYx = p[r + 8].x + __shfl_xor(p[r + 8].x, 16);
        float sYy = p[r + 8].y + __shfl_xor(p[r + 8].y, 16);
        p[r].x = k2 ? sYx : sXx;
        p[r].y = k2 ? sYy : sXy;
#endif
      }

      // ---- S3: xor8 via DPP row_ror:8 (ctrl 0x128), keep X at b3=0 ----
#pragma unroll
      for (int r = 0; r < 4; ++r) {
        float sXx = dpp_add<0x128>(p[r].x);
        float sXy = dpp_add<0x128>(p[r].y);
        float sYx = dpp_add<0x128>(p[r + 4].x);
        float sYy = dpp_add<0x128>(p[r + 4].y);
        p[r].x = k3 ? sYx : sXx;
        p[r].y = k3 ? sYy : sXy;
      }

      // ---- S4: xor7 via DPP row_half_mirror (ctrl 0x141), keep X at b2=0 --
#pragma unroll
      for (int r = 0; r < 2; ++r) {
        float sXx = dpp_add<0x141>(p[r].x);
        float sXy = dpp_add<0x141>(p[r].y);
        float sYx = dpp_add<0x141>(p[r + 2].x);
        float sYy = dpp_add<0x141>(p[r + 2].y);
        p[r].x = k4 ? sYx : sXx;
        p[r].y = k4 ? sYy : sXy;
      }

      // ---- S5: xor2 via DPP quad_perm[2,3,0,1] (ctrl 0x4E) ----
      {
        float sXx = dpp_add<0x4E>(p[0].x);
        float sXy = dpp_add<0x4E>(p[0].y);
        float sYx = dpp_add<0x4E>(p[1].x);
        float sYy = dpp_add<0x4E>(p[1].y);
        p[0].x = k5 ? sYx : sXx;
        p[0].y = k5 ? sYy : sXy;
      }

      // ---- S6: xor1 via DPP quad_perm[1,0,3,2] (ctrl 0xB1) ----
      float sX = dpp_add<0xB1>(p[0].x);
      float sY = dpp_add<0xB1>(p[0].y);
      float y = (k6 ? sY : sX) + a_cur;  // y[lane], exactly

      // tanh(y) = 1 - 2*rcp(exp(2y)+1)  (saturation-safe at both extremes)
      float ex = __builtin_amdgcn_exp2f(y * 2.88539008177792681f);  // exp(2y)
      h = fmaf(-2.f, __builtin_amdgcn_rcpf(ex + 1.f), 1.f);
    }
    if (c + 1 < SEQ / 64) {
      int tkb = __builtin_amdgcn_readlane(tokv[c + 1], 0);
      a = P[(long)tkb + lane];
    }
  }

  // out[row] = sigmoid(sum_j h[j]*Wout[j] + bout)
  float psum = h * Wout[lane];
#pragma unroll
  for (int off = 32; off > 0; off >>= 1) psum += __shfl_xor(psum, off);
  if (lane == 0) out[row] = 1.f / (1.f + __expf(-(psum + bout[0])));
}

extern "C" void kernel_launch(void* const* d_in, const int* in_sizes, int n_in,
                              void* d_out, int out_size, void* d_ws, size_t ws_size,
                              hipStream_t stream) {
  const int*   tok  = (const int*)  d_in[0];  // [BATCH, SEQ] int32
  const float* emb  = (const float*)d_in[1];  // [VOCAB, EMB]
  const float* Wxh  = (const float*)d_in[2];  // [EMB, UNITS]
  const float* Whh  = (const float*)d_in[3];  // [UNITS, UNITS]
  const float* bias = (const float*)d_in[4];  // [UNITS]
  const float* Wout = (const float*)d_in[5];  // [UNITS, 1]
  const float* bout = (const float*)d_in[6];  // [1]
  float* out = (float*)d_out;                 // [BATCH, 1] fp32

  float* P = (float*)d_ws;                    // VOCAB*UNITS fp32 = 256 KB

  proj_kernel<<<VOCAB / 4, 256, 0, stream>>>(emb, Wxh, bias, P);
  scan_kernel<<<BATCH, 64, 0, stream>>>(tok, P, Whh, Wout, bout, out);
}

// Round 3
// 174.382 us; speedup vs baseline: 1.6466x; 1.6466x over previous
//
#include <hip/hip_runtime.h>

#define BATCH 512
#define SEQ   512
#define VOCAB 1000
#define EMB   100
#define UNITS 64

typedef float v2f __attribute__((ext_vector_type(2)));
typedef float v4f __attribute__((ext_vector_type(4)));
typedef int   v2i __attribute__((ext_vector_type(2)));

// ---------------------------------------------------------------------------
// Kernel 1: P[v][u] = sum_d emb[v][d] * Wxh[d][u] + b[u]   (VOCAB x UNITS)
// ---------------------------------------------------------------------------
__global__ __launch_bounds__(256) void proj_kernel(
    const float* __restrict__ emb, const float* __restrict__ Wxh,
    const float* __restrict__ bias, float* __restrict__ P) {
  const int v = blockIdx.x * 4 + (threadIdx.x >> 6);
  const int u = threadIdx.x & 63;
  const float* e = emb + v * EMB;
  float a0 = 0.f, a1 = 0.f, a2 = 0.f, a3 = 0.f;
#pragma unroll
  for (int d = 0; d < EMB; d += 4) {
    a0 = fmaf(e[d + 0], Wxh[(d + 0) * UNITS + u], a0);
    a1 = fmaf(e[d + 1], Wxh[(d + 1) * UNITS + u], a1);
    a2 = fmaf(e[d + 2], Wxh[(d + 2) * UNITS + u], a2);
    a3 = fmaf(e[d + 3], Wxh[(d + 3) * UNITS + u], a3);
  }
  P[v * UNITS + u] = ((a0 + a1) + (a2 + a3)) + bias[u];
}

// ---------------------------------------------------------------------------
// Kernel 2: sequential scan, ONE wave per batch row (r1 structure, refined).
//   h[j] <- tanh(P[tok_t][j] + sum_i h[i]*Whh[i][j])
//
// r2 post-mortem: full register butterfly = ~200 VALU instr/step (permlane
// swap builtins cost swap+movs, dpp_add = mov_dpp+add) -> 2x SLOWER than the
// LDS broadcast path. LDS same-address broadcast distributes h for free.
//
// This version = r1 (LDS split) with two latency fixes:
//  (a) P-row prefetch distance TWO: the consumed value's load was issued
//      ~2 steps (~1000 cyc) earlier, so the compiler's s_waitcnt before the
//      y-add tolerates the in-flight younger loads (no vmcnt(0) stall on the
//      just-issued prefetch, which plausibly cost ~190 cyc/step in r1).
//  (b) Split-4: lane (g = l>>4, m = l&15) reads only h[16g..16g+16) = 4x
//      ds_read_b128 (read issue halved vs r1's 8). Read q targets
//      hs4[4g + ((q+g)&3)]: the g-rotation makes each read's 4 distinct
//      16B addresses split 2/2 across bank quads {0-3},{16-19} (2-way = free;
//      unrotated all 4 groups alias the same quad = 4-way = 1.58x).
//      Lane computes 4 partials (outputs m+16k over its 16 i's); merge:
//        stage A: permlane32_swap(s0,s2)->add, (s1,s3)->add   [verified r1]
//        stage B: permlane16_swap(u0,u1)->add  => y[l] lands at lane l.
// ---------------------------------------------------------------------------
__global__ __launch_bounds__(64)
__attribute__((amdgpu_waves_per_eu(1, 1)))
void scan_kernel(
    const int* __restrict__ tok, const float* __restrict__ P,
    const float* __restrict__ Whh, const float* __restrict__ Wout,
    const float* __restrict__ bout, float* __restrict__ out) {
  const int row  = blockIdx.x;
  const int lane = threadIdx.x;
  const int g    = lane >> 4;   // 16-lane group: i-range [16g, 16g+16)
  const int m    = lane & 15;

  __shared__ __align__(16) v4f hs4[UNITS / 4];  // 64 floats
  float* hsf = (float*)hs4;

  // Loop-invariant staggered LDS read addresses (4 VGPRs).
  const v4f* hp[4];
#pragma unroll
  for (int q = 0; q < 4; ++q) hp[q] = &hs4[4 * g + ((q + g) & 3)];

  // Weights: wv[k][2q+p] = {Whh[i0][m+16k], Whh[i0+1][m+16k]},
  // i0 = 16g + 4*((q+g)&3) + 2p  (matches the staggered read order).
  v2f wv[4][8];
#pragma unroll
  for (int q = 0; q < 4; ++q) {
    const int r = (q + g) & 3;
#pragma unroll
    for (int p = 0; p < 2; ++p) {
      const int i0 = 16 * g + 4 * r + 2 * p;
#pragma unroll
      for (int k = 0; k < 4; ++k) {
        float wx = Whh[(i0 + 0) * UNITS + m + 16 * k];
        float wy = Whh[(i0 + 1) * UNITS + m + 16 * k];
        asm volatile("" : "+v"(wx), "+v"(wy));
        wv[k][2 * q + p].x = wx;
        wv[k][2 * q + p].y = wy;
      }
    }
  }

  // All 512 tokens of this row, pre-scaled by UNITS (coalesced loads).
  int tokv[SEQ / 64];
  const int* trow = tok + (long)row * SEQ;
#pragma unroll
  for (int c = 0; c < SEQ / 64; ++c) {
    int t = trow[c * 64 + lane] * UNITS;
    asm volatile("" : "+v"(t));
    tokv[c] = t;
  }

  // h_0 = 0 (single wave: same-wave LDS ops are in-order, no barriers).
  hsf[lane] = 0.f;

  // Distance-2 P-row prefetch pipeline.
  int tk0 = __builtin_amdgcn_readlane(tokv[0], 0);
  int tk1 = __builtin_amdgcn_readlane(tokv[0], 1);
  float a0 = P[(long)tk0 + lane];
  float a1 = P[(long)tk1 + lane];

#pragma unroll
  for (int c = 0; c < SEQ / 64; ++c) {
#pragma unroll 4
    for (int tt = 0; tt < 64; ++tt) {
      // Prefetch token for step t+2 (c is compile-time; only tt is runtime).
      // For c==7, tt>=62 this fetches chunk-7 tokens again: a valid P index
      // whose loaded value is never consumed.
      const int cn = (c < SEQ / 64 - 1) ? c + 1 : c;
      int srctok = (tt < 62) ? tokv[c] : tokv[cn];
      int tk2 = __builtin_amdgcn_readlane(srctok, (tt + 2) & 63);
      float a_next = P[(long)tk2 + lane];

      // ---- Read MY 16 h values: 4x ds_read_b128, staggered order. ----
      v4f hq0 = *hp[0];
      v4f hq1 = *hp[1];
      v4f hq2 = *hp[2];
      v4f hq3 = *hp[3];

      // ---- 4 partials s_k (outputs m+16k), 2 chains of depth 4 each. ----
      v2f lo0; lo0.x = hq0.x; lo0.y = hq0.y;
      v2f hi0; hi0.x = hq0.z; hi0.y = hq0.w;
      v2f lo1; lo1.x = hq1.x; lo1.y = hq1.y;
      v2f hi1; hi1.x = hq1.z; hi1.y = hq1.w;
      v2f lo2; lo2.x = hq2.x; lo2.y = hq2.y;
      v2f hi2; hi2.x = hq2.z; hi2.y = hq2.w;
      v2f lo3; lo3.x = hq3.x; lo3.y = hq3.y;
      v2f hi3; hi3.x = hq3.z; hi3.y = hq3.w;

      float sk[4];
#pragma unroll
      for (int k = 0; k < 4; ++k) {
        v2f accA = lo0 * wv[k][0];
        accA += hi0 * wv[k][1];
        accA += lo1 * wv[k][2];
        accA += hi1 * wv[k][3];
        v2f accB = lo2 * wv[k][4];
        accB += hi2 * wv[k][5];
        accB += lo3 * wv[k][6];
        accB += hi3 * wv[k][7];
        v2f t = accA + accB;
        sk[k] = t.x + t.y;
      }

      // ---- Merge stage A (xor32): u at lane l = partial(out m+32*b5,
      //      i-ranges {b4, b4+2}). ----
      v2i swA0 = __builtin_amdgcn_permlane32_swap(
          __float_as_int(sk[0]), __float_as_int(sk[2]), false, false);
      float u0 = __int_as_float(swA0[0]) + __int_as_float(swA0[1]);
      v2i swA1 = __builtin_amdgcn_permlane32_swap(
          __float_as_int(sk[1]), __float_as_int(sk[3]), false, false);
      float u1 = __int_as_float(swA1[0]) + __int_as_float(swA1[1]);

      // ---- Merge stage B (xor16): y[l] lands exactly at lane l. ----
#if __has_builtin(__builtin_amdgcn_permlane16_swap)
      v2i swB = __builtin_amdgcn_permlane16_swap(
          __float_as_int(u0), __float_as_int(u1), false, false);
      float y = (__int_as_float(swB[0]) + __int_as_float(swB[1])) + a0;
#else
      float y0 = u0 + __shfl_xor(u0, 16);
      float y1 = u1 + __shfl_xor(u1, 16);
      float y = (((lane >> 4) & 1) ? y1 : y0) + a0;
#endif

      // tanh(y) = 1 - 2*rcp(exp(2y)+1)  (saturation-safe at both extremes)
      float ex = __builtin_amdgcn_exp2f(y * 2.88539008177792681f);  // exp(2y)
      float h = fmaf(-2.f, __builtin_amdgcn_rcpf(ex + 1.f), 1.f);

      // Publish h for the next step (in-order DS pipe, no barrier needed).
      hsf[lane] = h;

      // Rotate the prefetch pipeline.
      a0 = a1;
      a1 = a_next;
    }
  }

  // out[row] = sigmoid(sum_j h[j]*Wout[j] + bout); hsf[lane] holds h_T[lane].
  float psum = hsf[lane] * Wout[lane];
#pragma unroll
  for (int off = 32; off > 0; off >>= 1) psum += __shfl_xor(psum, off);
  if (lane == 0) out[row] = 1.f / (1.f + __expf(-(psum + bout[0])));
}

extern "C" void kernel_launch(void* const* d_in, const int* in_sizes, int n_in,
                              void* d_out, int out_size, void* d_ws, size_t ws_size,
                              hipStream_t stream) {
  const int*   tok  = (const int*)  d_in[0];  // [BATCH, SEQ] int32
  const float* emb  = (const float*)d_in[1];  // [VOCAB, EMB]
  const float* Wxh  = (const float*)d_in[2];  // [EMB, UNITS]
  const float* Whh  = (const float*)d_in[3];  // [UNITS, UNITS]
  const float* bias = (const float*)d_in[4];  // [UNITS]
  const float* Wout = (const float*)d_in[5];  // [UNITS, 1]
  const float* bout = (const float*)d_in[6];  // [1]
  float* out = (float*)d_out;                 // [BATCH, 1] fp32

  float* P = (float*)d_ws;                    // VOCAB*UNITS fp32 = 256 KB

  proj_kernel<<<VOCAB / 4, 256, 0, stream>>>(emb, Wxh, bias, P);
  scan_kernel<<<BATCH, 64, 0, stream>>>(tok, P, Whh, Wout, bout, out);
}

// Round 4
// 168.017 us; speedup vs baseline: 1.7090x; 1.0379x over previous
//
#include <hip/hip_runtime.h>

#define BATCH 512
#define SEQ   512
#define VOCAB 1000
#define EMB   100
#define UNITS 64

// 2*log2(e): fold tanh's exp(2y)=exp2(K*y) scale into P and Whh at load time.
#define KSCALE 2.885390081777926814f

typedef float v2f __attribute__((ext_vector_type(2)));
typedef int   v2i __attribute__((ext_vector_type(2)));

// ---------------------------------------------------------------------------
// Kernel 1: P[v][u] = (sum_d emb[v][d] * Wxh[d][u] + b[u]) * KSCALE
// ---------------------------------------------------------------------------
__global__ __launch_bounds__(256) void proj_kernel(
    const float* __restrict__ emb, const float* __restrict__ Wxh,
    const float* __restrict__ bias, float* __restrict__ P) {
  const int v = blockIdx.x * 4 + (threadIdx.x >> 6);
  const int u = threadIdx.x & 63;
  const float* e = emb + v * EMB;
  float a0 = 0.f, a1 = 0.f, a2 = 0.f, a3 = 0.f;
#pragma unroll
  for (int d = 0; d < EMB; d += 4) {
    a0 = fmaf(e[d + 0], Wxh[(d + 0) * UNITS + u], a0);
    a1 = fmaf(e[d + 1], Wxh[(d + 1) * UNITS + u], a1);
    a2 = fmaf(e[d + 2], Wxh[(d + 2) * UNITS + u], a2);
    a3 = fmaf(e[d + 3], Wxh[(d + 3) * UNITS + u], a3);
  }
  P[v * UNITS + u] = (((a0 + a1) + (a2 + a3)) + bias[u]) * KSCALE;
}

template <int CTRL>
__device__ __forceinline__ float dppmov(float x) {
  return __int_as_float(
      __builtin_amdgcn_update_dpp(0, __float_as_int(x), CTRL, 0xF, 0xF, true));
}

// ---------------------------------------------------------------------------
// Kernel 2: sequential scan, ONE wave per batch row. ZERO memory ops on the
// recurrence chain.
//   h[j] <- tanh(P[tok_t][j] + sum_i h[i]*Whh[i][j])
//
// r3 post-mortem: the LDS h-publish round trip (write -> in-order DS pipe ->
// read latency) is ~250+ cyc of the 532-cyc step; read-count tuning can't fix
// it. r2's full butterfly removed LDS but cost ~200 VALU instrs.
//
// This version: 4-stage DPP register ALL-GATHER (15 v_mov_dpp total). Lane
// (R = l>>4, m = l&15) needs only h[16R .. 16R+16) -- all within its own
// 16-lane DPP row. Gather with involutions only (direction-unambiguous):
//   s[0] = own h                       s[1]    = xor1  (quad_perm 0xB1)
//   s[2..3]  = xor2 of s[0..1]         (quad_perm 0x4E)
//   s[4..7]  = xor7 of s[0..3]         (row_half_mirror 0x141)
//   s[8..15] = xor8 of s[0..7]         (row_ror:8 0x128)
// Slot j holds h[16R + (m ^ X[j])], X = {0,1,2,3,7,6,5,4,8,9,10,11,
// 15,14,13,12} -- absorbed into the per-lane weight layout. Partials sk[k]
// (output m+16k over i-chunk R) are IDENTICAL to r3's, so r3's verified
// 2-stage permlane32/16_swap merge is reused verbatim. P and Whh are
// pre-scaled by KSCALE so tanh needs no chain multiply.
// ---------------------------------------------------------------------------
__global__ __launch_bounds__(64)
__attribute__((amdgpu_waves_per_eu(1, 1)))
void scan_kernel(
    const int* __restrict__ tok, const float* __restrict__ P,
    const float* __restrict__ Whh, const float* __restrict__ Wout,
    const float* __restrict__ bout, float* __restrict__ out) {
  const int row  = blockIdx.x;
  const int lane = threadIdx.x;
  const int R    = lane >> 4;   // i-chunk: [16R, 16R+16)
  const int m    = lane & 15;

  // Slot -> h-index xor pattern (see header comment).
  const int X[16] = {0, 1, 2, 3, 7, 6, 5, 4, 8, 9, 10, 11, 15, 14, 13, 12};

  // Weights, KSCALE-pre-scaled, slot-order-matched:
  //   w2[t][k] = { K*Whh[16R + (m^X[2t])][m+16k], K*Whh[16R+(m^X[2t+1])][m+16k] }
  v2f w2[8][4];
#pragma unroll
  for (int t = 0; t < 8; ++t) {
    const int ix = 16 * R + (m ^ X[2 * t + 0]);
    const int iy = 16 * R + (m ^ X[2 * t + 1]);
#pragma unroll
    for (int k = 0; k < 4; ++k) {
      float wx = Whh[ix * UNITS + m + 16 * k] * KSCALE;
      float wy = Whh[iy * UNITS + m + 16 * k] * KSCALE;
      asm volatile("" : "+v"(wx), "+v"(wy));
      w2[t][k].x = wx;
      w2[t][k].y = wy;
    }
  }

  // All 512 tokens of this row, pre-scaled by UNITS (coalesced loads).
  int tokv[SEQ / 64];
  const int* trow = tok + (long)row * SEQ;
#pragma unroll
  for (int c = 0; c < SEQ / 64; ++c) {
    int t = trow[c * 64 + lane] * UNITS;
    asm volatile("" : "+v"(t));
    tokv[c] = t;
  }

  float h = 0.f;  // h[lane], register-resident for the whole scan

  // Distance-2 P-row prefetch pipeline (off-chain; covers L2 latency).
  int tk0 = __builtin_amdgcn_readlane(tokv[0], 0);
  int tk1 = __builtin_amdgcn_readlane(tokv[0], 1);
  float a0 = P[(long)tk0 + lane];
  float a1 = P[(long)tk1 + lane];

#pragma unroll
  for (int c = 0; c < SEQ / 64; ++c) {
#pragma unroll 2
    for (int tt = 0; tt < 64; ++tt) {
      // Prefetch P row for step t+2 (c==7 tail repeats chunk 7: valid index,
      // value never consumed).
      const int cn = (c < SEQ / 64 - 1) ? c + 1 : c;
      int srctok = (tt < 62) ? tokv[c] : tokv[cn];
      int tk2 = __builtin_amdgcn_readlane(srctok, (tt + 2) & 63);
      float a_next = P[(long)tk2 + lane];

      // ---- 4-stage DPP all-gather: s[j] = h[16R + (m^X[j])]. ----
      float s[16];
      s[0] = h;
      s[1] = dppmov<0xB1>(s[0]);                       // xor1
      s[2] = dppmov<0x4E>(s[0]);                       // xor2
      s[3] = dppmov<0x4E>(s[1]);
#pragma unroll
      for (int j = 0; j < 4; ++j) s[4 + j] = dppmov<0x141>(s[j]);   // xor7
#pragma unroll
      for (int j = 0; j < 8; ++j) s[8 + j] = dppmov<0x128>(s[j]);   // xor8

      // ---- 4 partials sk[k] (output m+16k over i in [16R,16R+16)). ----
      // Early slots (ready first) feed chain A; late slots chain B.
      float sk[4];
#pragma unroll
      for (int k = 0; k < 4; ++k) {
        v2f ca, cb;
        ca.x = s[0] * w2[0][k].x; ca.y = s[1] * w2[0][k].y;
        cb.x = s[8] * w2[4][k].x; cb.y = s[9] * w2[4][k].y;
#pragma unroll
        for (int t = 1; t < 4; ++t) {
          v2f e, l;
          e.x = s[2 * t];     e.y = s[2 * t + 1];
          l.x = s[2 * t + 8]; l.y = s[2 * t + 9];
          ca += e * w2[t][k];
          cb += l * w2[t + 4][k];
        }
        v2f r = ca + cb;
        sk[k] = r.x + r.y;
      }

      // ---- Merge (r3-verified): stage A xor32, stage B xor16. ----
      v2i swA0 = __builtin_amdgcn_permlane32_swap(
          __float_as_int(sk[0]), __float_as_int(sk[2]), false, false);
      float u0 = __int_as_float(swA0[0]) + __int_as_float(swA0[1]);
      v2i swA1 = __builtin_amdgcn_permlane32_swap(
          __float_as_int(sk[1]), __float_as_int(sk[3]), false, false);
      float u1 = __int_as_float(swA1[0]) + __int_as_float(swA1[1]);
#if __has_builtin(__builtin_amdgcn_permlane16_swap)
      v2i swB = __builtin_amdgcn_permlane16_swap(
          __float_as_int(u0), __float_as_int(u1), false, false);
      float y = (__int_as_float(swB[0]) + __int_as_float(swB[1])) + a0;
#else
      float y0 = u0 + __shfl_xor(u0, 16);
      float y1 = u1 + __shfl_xor(u1, 16);
      float y = (((lane >> 4) & 1) ? y1 : y0) + a0;
#endif

      // y is pre-scaled by K=2*log2(e):  tanh = 1 - 2*rcp(exp2(y)+1).
      float ex = __builtin_amdgcn_exp2f(y);
      h = fmaf(-2.f, __builtin_amdgcn_rcpf(ex + 1.f), 1.f);

      // Rotate the prefetch pipeline.
      a0 = a1;
      a1 = a_next;
    }
  }

  // out[row] = sigmoid(sum_j h[j]*Wout[j] + bout)
  float psum = h * Wout[lane];
#pragma unroll
  for (int off = 32; off > 0; off >>= 1) psum += __shfl_xor(psum, off);
  if (lane == 0) out[row] = 1.f / (1.f + __expf(-(psum + bout[0])));
}

extern "C" void kernel_launch(void* const* d_in, const int* in_sizes, int n_in,
                              void* d_out, int out_size, void* d_ws, size_t ws_size,
                              hipStream_t stream) {
  const int*   tok  = (const int*)  d_in[0];  // [BATCH, SEQ] int32
  const float* emb  = (const float*)d_in[1];  // [VOCAB, EMB]
  const float* Wxh  = (const float*)d_in[2];  // [EMB, UNITS]
  const float* Whh  = (const float*)d_in[3];  // [UNITS, UNITS]
  const float* bias = (const float*)d_in[4];  // [UNITS]
  const float* Wout = (const float*)d_in[5];  // [UNITS, 1]
  const float* bout = (const float*)d_in[6];  // [1]
  float* out = (float*)d_out;                 // [BATCH, 1] fp32

  float* P = (float*)d_ws;                    // VOCAB*UNITS fp32 = 256 KB

  proj_kernel<<<VOCAB / 4, 256, 0, stream>>>(emb, Wxh, bias, P);
  scan_kernel<<<BATCH, 64, 0, stream>>>(tok, P, Whh, Wout, bout, out);
}